// Round 4
// baseline (49.522 us; speedup 1.0000x reference)
//
#include <hip/hip_runtime.h>
#include <math.h>

#define NN 1024
#define DD 64
#define TPB 512

// One block per node, 512 threads = 8 waves, 4 blocks/CU (32 waves/CU).
// Phase 1: float2 ballot-compaction of adj[n,:] into sorted LDS index list.
// Phase 2: dense unroll-8 loop over live indices; unconditional coalesced
//          float4 loads (16 lanes x 16 B = one 256 B neigh row per group).
// Phase 3: shfl + LDS reduction, mean, 64x64 mat-vec vs W, add self, ReLU.
__global__ __launch_bounds__(TPB, 8) void mean_agg_kernel(
    const float* __restrict__ adj,
    const float* __restrict__ nr,
    const float* __restrict__ ni,
    const float* __restrict__ sr,
    const float* __restrict__ si,
    const float* __restrict__ W,
    float* __restrict__ out)
{
    const int n    = blockIdx.x;
    const int t    = threadIdx.x;
    const int wv   = t >> 6;
    const int lane = t & 63;

    __shared__ int   idx[NN];       // compacted nonzero m indices (sorted)
    __shared__ int   wcnt[8];       // per-wave nonzero counts
    __shared__ float lr[8][DD];
    __shared__ float li[8][DD];
    __shared__ float mean_s[2][DD];

    const float* __restrict__ adj_row = adj + (size_t)n * NN;

    // ---- Phase 1: float2 stream compaction (wave wv owns m in [wv*128, wv*128+128)) ----
    const float2 av = *reinterpret_cast<const float2*>(adj_row + t * 2);
    const bool f0 = (av.x != 0.f);
    const bool f1 = (av.y != 0.f);
    const unsigned long long mask0 = __ballot(f0);
    const unsigned long long mask1 = __ballot(f1);
    if (lane == 0) wcnt[wv] = __popcll(mask0) + __popcll(mask1);
    __syncthreads();

    int base = 0, cnt = 0;
    #pragma unroll
    for (int w = 0; w < 8; ++w) {
        if (w < wv) base += wcnt[w];
        cnt += wcnt[w];
    }

    const unsigned long long lm = (lane == 63) ? 0x7fffffffffffffffULL
                                               : ((1ULL << lane) - 1ULL);
    const int laneBase = base + __popcll(mask0 & lm) + __popcll(mask1 & lm);
    if (f0) idx[laneBase] = t * 2;                    // m = 2t
    if (f1) idx[laneBase + (f0 ? 1 : 0)] = t * 2 + 1; // m = 2t+1
    __syncthreads();

    // ---- Phase 2: dense accumulation over live neighbors ----
    const int d4 = t & 15;   // float4 column group
    const int mo = t >> 4;   // 0..31 (32 index-groups)

    const float* __restrict__ nr_row = nr + (size_t)n * (NN * DD);
    const float* __restrict__ ni_row = ni + (size_t)n * (NN * DD);

    float4 ar = make_float4(0.f, 0.f, 0.f, 0.f);
    float4 ai = make_float4(0.f, 0.f, 0.f, 0.f);

    #pragma unroll 8
    for (int k = mo; k < cnt; k += 32) {
        const int m = idx[k];                 // LDS broadcast within 16-lane group
        const float4 vr = *reinterpret_cast<const float4*>(nr_row + m * DD + d4 * 4);
        const float4 vi = *reinterpret_cast<const float4*>(ni_row + m * DD + d4 * 4);
        ar.x += vr.x; ar.y += vr.y; ar.z += vr.z; ar.w += vr.w;
        ai.x += vi.x; ai.y += vi.y; ai.z += vi.z; ai.w += vi.w;
    }

    // ---- Phase 3a: within-wave reduction (lanes sharing d4) ----
    for (int off = 16; off < 64; off <<= 1) {
        ar.x += __shfl_xor(ar.x, off);
        ar.y += __shfl_xor(ar.y, off);
        ar.z += __shfl_xor(ar.z, off);
        ar.w += __shfl_xor(ar.w, off);
        ai.x += __shfl_xor(ai.x, off);
        ai.y += __shfl_xor(ai.y, off);
        ai.z += __shfl_xor(ai.z, off);
        ai.w += __shfl_xor(ai.w, off);
    }

    if (lane < 16) {
        *reinterpret_cast<float4*>(&lr[wv][lane * 4]) = ar;
        *reinterpret_cast<float4*>(&li[wv][lane * 4]) = ai;
    }
    __syncthreads();

    // ---- Phase 3b: cross-wave reduce + mean (with non-finite -> 0) ----
    if (t < 128) {
        const int part = t >> 6;      // 0 = real, 1 = imag
        const int d    = t & 63;
        const float* ls = part ? &li[0][0] : &lr[0][0];
        float s = 0.f;
        #pragma unroll
        for (int w = 0; w < 8; ++w) s += ls[w * DD + d];
        float mean = s / (float)cnt;
        if (!isfinite(mean)) mean = 0.f;   // deg==0 -> 0 (nan2zero + inf2zero)
        mean_s[part][d] = mean;
    }
    __syncthreads();

    // ---- Phase 3c: mean @ W, add self, ReLU ----
    if (t < 128) {
        const int part = t >> 6;
        const int dq   = t & 63;
        const float* __restrict__ mv = mean_s[part];
        float acc = 0.f;
        #pragma unroll
        for (int d = 0; d < DD; ++d)
            acc = fmaf(mv[d], W[d * DD + dq], acc);   // mv[d] broadcast, W coalesced
        const float* __restrict__ selfv = part ? si : sr;
        const float o = selfv[n * DD + dq] + acc;
        out[(size_t)part * (NN * DD) + n * DD + dq] = fmaxf(o, 0.f);
    }
}

extern "C" void kernel_launch(void* const* d_in, const int* in_sizes, int n_in,
                              void* d_out, int out_size, void* d_ws, size_t ws_size,
                              hipStream_t stream) {
    const float* adj = (const float*)d_in[0];
    const float* nr  = (const float*)d_in[1];
    const float* ni  = (const float*)d_in[2];
    const float* sr  = (const float*)d_in[3];
    const float* si  = (const float*)d_in[4];
    const float* W   = (const float*)d_in[5];
    float* out = (float*)d_out;

    mean_agg_kernel<<<dim3(NN), dim3(TPB), 0, stream>>>(adj, nr, ni, sr, si, W, out);
}

// Round 5
// 46.545 us; speedup vs baseline: 1.0640x; 1.0640x over previous
//
#include <hip/hip_runtime.h>
#include <math.h>

#define NN 1024
#define DD 64
#define TPB 512

// One block per node, 512 threads = 8 waves, grid-limited 4 blocks/CU.
// Phase 1: ballot-compaction of adj[n,:] into sorted LDS index list (round-3).
// Phase 2: each 16-lane group owns 4 CONSECUTIVE compacted indices per macro
//          iteration (int4 ds_read_b128 broadcast), so adjacent live rows give
//          contiguous 256 B request runs that merge into larger DRAM bursts.
// Phase 3: shfl + LDS reduction, mean, 64x64 mat-vec vs W, add self, ReLU.
__global__ __launch_bounds__(TPB) void mean_agg_kernel(
    const float* __restrict__ adj,
    const float* __restrict__ nr,
    const float* __restrict__ ni,
    const float* __restrict__ sr,
    const float* __restrict__ si,
    const float* __restrict__ W,
    float* __restrict__ out)
{
    const int n    = blockIdx.x;
    const int t    = threadIdx.x;
    const int wv   = t >> 6;
    const int lane = t & 63;

    __shared__ __align__(16) int idx[NN];  // compacted nonzero m indices (sorted)
    __shared__ int   wcnt[8];              // per-wave nonzero counts
    __shared__ float lr[8][DD];
    __shared__ float li[8][DD];
    __shared__ float mean_s[2][DD];

    const float* __restrict__ adj_row = adj + (size_t)n * NN;

    // ---- Phase 1: stream compaction (wave wv owns m in [wv*128, wv*128+128)) ----
    const int   m0 = wv * 128 + lane;
    const int   m1 = m0 + 64;
    const float a0 = adj_row[m0];
    const float a1 = adj_row[m1];
    const unsigned long long mask0 = __ballot(a0 != 0.f);
    const unsigned long long mask1 = __ballot(a1 != 0.f);
    const int c0 = __popcll(mask0);
    const int c1 = __popcll(mask1);
    if (lane == 0) wcnt[wv] = c0 + c1;
    __syncthreads();

    int base = 0, cnt = 0;
    #pragma unroll
    for (int w = 0; w < 8; ++w) {
        if (w < wv) base += wcnt[w];
        cnt += wcnt[w];
    }

    const unsigned long long lm = (lane == 63) ? 0x7fffffffffffffffULL
                                               : ((1ULL << lane) - 1ULL);
    if (a0 != 0.f) idx[base + __popcll(mask0 & lm)] = m0;
    if (a1 != 0.f) idx[base + c0 + __popcll(mask1 & lm)] = m1;
    __syncthreads();

    // ---- Phase 2: dense accumulation, 4 consecutive live rows per group ----
    const int d4 = t & 15;   // float4 column group within a row
    const int g  = t >> 4;   // 0..31 index group

    const float* __restrict__ nr_row = nr + (size_t)n * (NN * DD);
    const float* __restrict__ ni_row = ni + (size_t)n * (NN * DD);

    float4 ar = make_float4(0.f, 0.f, 0.f, 0.f);
    float4 ai = make_float4(0.f, 0.f, 0.f, 0.f);

    const int nfull = cnt & ~127;   // full 128-index macro iterations
    for (int kb = g * 4; kb < nfull; kb += 128) {
        const int4 mi = *reinterpret_cast<const int4*>(&idx[kb]);  // b128 broadcast
        const float4 r0 = *reinterpret_cast<const float4*>(nr_row + mi.x * DD + d4 * 4);
        const float4 r1 = *reinterpret_cast<const float4*>(nr_row + mi.y * DD + d4 * 4);
        const float4 r2 = *reinterpret_cast<const float4*>(nr_row + mi.z * DD + d4 * 4);
        const float4 r3 = *reinterpret_cast<const float4*>(nr_row + mi.w * DD + d4 * 4);
        const float4 i0 = *reinterpret_cast<const float4*>(ni_row + mi.x * DD + d4 * 4);
        const float4 i1 = *reinterpret_cast<const float4*>(ni_row + mi.y * DD + d4 * 4);
        const float4 i2 = *reinterpret_cast<const float4*>(ni_row + mi.z * DD + d4 * 4);
        const float4 i3 = *reinterpret_cast<const float4*>(ni_row + mi.w * DD + d4 * 4);
        ar.x += r0.x + r1.x + r2.x + r3.x;
        ar.y += r0.y + r1.y + r2.y + r3.y;
        ar.z += r0.z + r1.z + r2.z + r3.z;
        ar.w += r0.w + r1.w + r2.w + r3.w;
        ai.x += i0.x + i1.x + i2.x + i3.x;
        ai.y += i0.y + i1.y + i2.y + i3.y;
        ai.z += i0.z + i1.z + i2.z + i3.z;
        ai.w += i0.w + i1.w + i2.w + i3.w;
    }
    // tail: remaining cnt - nfull (< 128) indices, one per group round-robin
    for (int k = nfull + g; k < cnt; k += 32) {
        const int m = idx[k];
        const float4 vr = *reinterpret_cast<const float4*>(nr_row + m * DD + d4 * 4);
        const float4 vi = *reinterpret_cast<const float4*>(ni_row + m * DD + d4 * 4);
        ar.x += vr.x; ar.y += vr.y; ar.z += vr.z; ar.w += vr.w;
        ai.x += vi.x; ai.y += vi.y; ai.z += vi.z; ai.w += vi.w;
    }

    // ---- Phase 3a: within-wave reduction (lanes sharing d4) ----
    for (int off = 16; off < 64; off <<= 1) {
        ar.x += __shfl_xor(ar.x, off);
        ar.y += __shfl_xor(ar.y, off);
        ar.z += __shfl_xor(ar.z, off);
        ar.w += __shfl_xor(ar.w, off);
        ai.x += __shfl_xor(ai.x, off);
        ai.y += __shfl_xor(ai.y, off);
        ai.z += __shfl_xor(ai.z, off);
        ai.w += __shfl_xor(ai.w, off);
    }

    if (lane < 16) {
        *reinterpret_cast<float4*>(&lr[wv][lane * 4]) = ar;
        *reinterpret_cast<float4*>(&li[wv][lane * 4]) = ai;
    }
    __syncthreads();

    // ---- Phase 3b: cross-wave reduce + mean (with non-finite -> 0) ----
    if (t < 128) {
        const int part = t >> 6;      // 0 = real, 1 = imag
        const int d    = t & 63;
        const float* ls = part ? &li[0][0] : &lr[0][0];
        float s = 0.f;
        #pragma unroll
        for (int w = 0; w < 8; ++w) s += ls[w * DD + d];
        float mean = s / (float)cnt;
        if (!isfinite(mean)) mean = 0.f;   // deg==0 -> 0 (nan2zero + inf2zero)
        mean_s[part][d] = mean;
    }
    __syncthreads();

    // ---- Phase 3c: mean @ W, add self, ReLU ----
    if (t < 128) {
        const int part = t >> 6;
        const int dq   = t & 63;
        const float* __restrict__ mv = mean_s[part];
        float acc = 0.f;
        #pragma unroll
        for (int d = 0; d < DD; ++d)
            acc = fmaf(mv[d], W[d * DD + dq], acc);   // mv[d] broadcast, W coalesced
        const float* __restrict__ selfv = part ? si : sr;
        const float o = selfv[n * DD + dq] + acc;
        out[(size_t)part * (NN * DD) + n * DD + dq] = fmaxf(o, 0.f);
    }
}

extern "C" void kernel_launch(void* const* d_in, const int* in_sizes, int n_in,
                              void* d_out, int out_size, void* d_ws, size_t ws_size,
                              hipStream_t stream) {
    const float* adj = (const float*)d_in[0];
    const float* nr  = (const float*)d_in[1];
    const float* ni  = (const float*)d_in[2];
    const float* sr  = (const float*)d_in[3];
    const float* si  = (const float*)d_in[4];
    const float* W   = (const float*)d_in[5];
    float* out = (float*)d_out;

    mean_agg_kernel<<<dim3(NN), dim3(TPB), 0, stream>>>(adj, nr, ni, sr, si, W, out);
}